// Round 7
// baseline (196.413 us; speedup 1.0000x reference)
//
#include <hip/hip_runtime.h>
#include <math.h>

#define NGRID 9801
#define NB 11            // blocks per dim (both scales)
#define NBLK (NB*NB)     // 121
#define BATCH 16
#define NFEAT 36

// ---------------- tables ----------------
__global__ void init_tables(float* __restrict__ rgam, float* __restrict__ convt,
                            float* __restrict__ meanf, float* __restrict__ w1d) {
    int i = blockIdx.x * blockDim.x + threadIdx.x;
    if (i < NGRID) {
        double a = (double)(float)(0.2 + 0.001 * (double)i);  // match float32 grid
        double g1 = lgamma(1.0 / a);
        double g2 = lgamma(2.0 / a);
        double g3 = lgamma(3.0 / a);
        rgam[i]  = (float)exp(2.0 * g2 - g1 - g3);
        convt[i] = (float)sqrt(exp(g1 - g3));
        meanf[i] = (float)exp(g2 - g1);
    }
    if (i == 0) {
        double g[7], s = 0.0;
        for (int k = 0; k < 7; ++k) { double d = (double)(k - 3); g[k] = exp(-d * d * 18.0 / 49.0); s += g[k]; }
        for (int k = 0; k < 7; ++k) w1d[k] = (float)(g[k] / s);
    }
}

__device__ __forceinline__ float bperm(int addr, float v) {
    return __int_as_float(__builtin_amdgcn_ds_bpermute(addr, __float_as_int(v)));
}

// ================= scale-1: float2 fused MSCN + stats + downsample =============
// One WG per (96-block, batch). 4 waves = 4 strips of 24 rows. Each lane owns
// an input PAIR (cols x0-4+2l, x0-3+2l); lanes 0..47 own output pairs
// (cols 2l, 2l+1). Whole block width in one wave -> no column seams.
// Ring arrays are depth-8 with compile-time (c+k)&7 indices (inner unroll 8).
__global__ __launch_bounds__(256) void fused96(
        const float* __restrict__ img, float* __restrict__ dsout,
        const float* __restrict__ w1d, float* __restrict__ stats) {
    constexpr int K = 96, W = 1056, H = 1056, SROWS = 24;
    __shared__ float2 lastrow2[4][48];
    __shared__ float redf[4][15];
    __shared__ float redc[4][10];

    const int tid = threadIdx.x;
    const int lane = tid & 63;
    const int strip = tid >> 6;
    const int bIdx = blockIdx.x;
    const int b = blockIdx.y;
    const int bh = bIdx / NB, bw = bIdx % NB;
    const int x0 = bw * K;
    const int c0 = x0 - 4 + 2 * lane;
    const int cc = min(max(c0, 0), W - 2);
    const bool fixL = (c0 < 0), fixR = (c0 >= W);
    const int r0 = bh * K + strip * SROWS;
    const bool act = lane < 48;

    // hconv neighbor-pair bperm byte addrs
    const int aP1 = ((lane + 1) & 63) << 2;
    const int aP2 = ((lane + 2) & 63) << 2;
    const int aP3 = ((lane + 3) & 63) << 2;
    const int aP4 = ((lane + 4) & 63) << 2;
    // block-circular product addrs (within the 48 output lanes)
    const int aL = (act ? (lane == 0 ? 47 : lane - 1) : 0) << 2;
    const int aR = (act ? (lane == 47 ? 0 : lane + 1) : 0) << 2;

    const float* imb = img + (size_t)b * H * W;     // uniform base
    int roff = max(r0 - 3, 0) * W;                  // uniform row offset (floats)
    int row = r0 - 3;                               // uniform next-load row
    const float w0=w1d[0], w1=w1d[1], w2=w1d[2], w3=w1d[3], w4=w1d[4], w5=w1d[5], w6=w1d[6];

    auto ldrow = [&]() -> float2 {
        float2 u = *(const float2*)(imb + roff + cc);
        u.y = fixL ? u.x : u.y;
        u.x = fixR ? u.y : u.x;
        roff += (row >= 0 && row < H - 1) ? W : 0;  // uniform -> SALU
        ++row;
        return u;
    };

    // pending hconv inputs for one raw row (8 taps spanning both outputs)
    float ay, bx, by, cx, cy, dx, dy, ex;
    auto issue_raw = [&](float2 u) {
        ay = u.y;
        bx = bperm(aP1, u.x); by = bperm(aP1, u.y);
        cx = bperm(aP2, u.x); cy = bperm(aP2, u.y);
        dx = bperm(aP3, u.x); dy = bperm(aP3, u.y);
        ex = bperm(aP4, u.x);
    };
    auto combine_raw = [&](float2& m, float2& q) -> float2 {
        m.x = ((w0*ay + w1*bx) + (w2*by + w3*cx)) + ((w4*cy + w5*dx) + w6*dy);
        m.y = ((w0*bx + w1*by) + (w2*cx + w3*cy)) + ((w4*dx + w5*dy) + w6*ex);
        float say=ay*ay, sbx=bx*bx, sby=by*by, scx=cx*cx, scy=cy*cy, sdx=dx*dx, sdy=dy*dy, sex=ex*ex;
        q.x = ((w0*say + w1*sbx) + (w2*sby + w3*scx)) + ((w4*scy + w5*sdx) + w6*sdy);
        q.y = ((w0*sbx + w1*sby) + (w2*scx + w3*scy)) + ((w4*sdx + w5*sdy) + w6*sex);
        float2 rc; rc.x = cx; rc.y = cy;
        return rc;
    };

    float acc[5][3];
    #pragma unroll
    for (int s = 0; s < 5; ++s) { acc[s][0] = acc[s][1] = acc[s][2] = 0.f; }
    int cl[5] = {0,0,0,0,0}, cr[5] = {0,0,0,0,0};
    auto upd2 = [&](int s, float vx, float vy) {
        float px = fmaxf(vx, 0.f), py = fmaxf(vy, 0.f);
        acc[s][0] = fmaf(px, px, fmaf(py, py, acc[s][0]));  // sr2
        acc[s][1] = fmaf(vx, vx, fmaf(vy, vy, acc[s][1]));  // ssq
        acc[s][2] += fabsf(vx) + fabsf(vy);                 // sab
        cl[s] += __popcll(__ballot(vx < 0.f)) + __popcll(__ballot(vy < 0.f));
        cr[s] += __popcll(__ballot(vx > 0.f)) + __popcll(__ballot(vy > 0.f));
    };

    // ---- prologue: rows r0-3..r0+3 into rings; pends=row r0+4; preload +5,+6
    float2 m2[8], q2[8], rawc[8];
    #pragma unroll
    for (int t = -3; t <= 3; ++t) {
        float2 u = ldrow();
        issue_raw(u);
        float2 rc = combine_raw(m2[(t + 3) & 7], q2[(t + 3) & 7]);
        if (t >= 0) rawc[t & 7] = rc;
    }
    { float2 u = ldrow(); issue_raw(u); }
    float2 vn0 = ldrow();
    float2 vn1 = ldrow();

    float2 prev; prev.x = prev.y = 0.f;
    float2 prev2; prev2.x = prev2.y = 0.f;
    float pendSL = 0.f, pendPL = 0.f, pendPR = 0.f;
    float2 firstN; firstN.x = firstN.y = 0.f;
    float dsSave = 0.f;
    float* dsp = dsout + ((size_t)b * (H / 2) + (r0 >> 1)) * (W / 2) + (bw * 48 + (act ? lane : 0));

    auto do_stats = [&]() {
        upd2(0, prev.x, prev.y);
        upd2(1, prev.x * pendSL,  prev.y * prev.x);
        upd2(2, prev.x * prev2.x, prev.y * prev2.y);
        upd2(3, prev.x * pendPL,  prev.y * prev2.x);
        upd2(4, prev.x * prev2.y, prev.y * pendPR);
    };

    #pragma unroll 1
    for (int yo = 0; yo < 3; ++yo) {
        #pragma unroll
        for (int c = 0; c < 8; ++c) {
            // 1) stats for previous row (pend product bperms issued last iter)
            if (c > 0) { do_stats(); }
            else if (yo > 0) { do_stats(); }

            // 2) vertical combine for this row -> norm pair
            float mux = ((w0*m2[c&7].x + w1*m2[(c+1)&7].x) + (w2*m2[(c+2)&7].x + w3*m2[(c+3)&7].x))
                      + ((w4*m2[(c+4)&7].x + w5*m2[(c+5)&7].x) + w6*m2[(c+6)&7].x);
            float muy = ((w0*m2[c&7].y + w1*m2[(c+1)&7].y) + (w2*m2[(c+2)&7].y + w3*m2[(c+3)&7].y))
                      + ((w4*m2[(c+4)&7].y + w5*m2[(c+5)&7].y) + w6*m2[(c+6)&7].y);
            float s2x = ((w0*q2[c&7].x + w1*q2[(c+1)&7].x) + (w2*q2[(c+2)&7].x + w3*q2[(c+3)&7].x))
                      + ((w4*q2[(c+4)&7].x + w5*q2[(c+5)&7].x) + w6*q2[(c+6)&7].x);
            float s2y = ((w0*q2[c&7].y + w1*q2[(c+1)&7].y) + (w2*q2[(c+2)&7].y + w3*q2[(c+3)&7].y))
                      + ((w4*q2[(c+4)&7].y + w5*q2[(c+5)&7].y) + w6*q2[(c+6)&7].y);
            float2 rA = rawc[c & 7];
            float nx = (rA.x - mux) * __builtin_amdgcn_rcpf(__builtin_amdgcn_sqrtf(fabsf(s2x - mux*mux)) + 1.0f);
            float ny = (rA.y - muy) * __builtin_amdgcn_rcpf(__builtin_amdgcn_sqrtf(fabsf(s2y - muy*muy)) + 1.0f);
            float2 cur; cur.x = act ? nx : 0.f; cur.y = act ? ny : 0.f;

            // 3) captures
            if (c == 0 && yo == 0) firstN = cur;
            if (c == 7 && yo == 2 && act) lastrow2[strip][lane] = cur;

            // 4) fused 2x2-mean downsample (both cols in-lane)
            float hs = rA.x + rA.y;
            if ((c & 1) == 0) { dsSave = hs; }
            else {
                if (act) *dsp = 0.25f * (dsSave + hs);
                dsp += (W / 2);
            }

            // 5) issue product bperms for next iteration
            pendSL = bperm(aL, cur.y);
            pendPL = bperm(aL, prev.y);
            pendPR = bperm(aR, prev.x);
            prev2 = prev; prev = cur;

            // 6) combine pend raw row (y+4) -> push rings
            rawc[(c + 4) & 7] = combine_raw(m2[(c + 7) & 7], q2[(c + 7) & 7]);

            // 7) rotate 2-deep load pipeline; issue raw bperms for row y+5
            if ((c & 1) == 0) { float2 t = vn0; vn0 = ldrow(); issue_raw(t); }
            else              { float2 t = vn1; vn1 = ldrow(); issue_raw(t); }
        }
    }
    // epilogue: stats for the strip's last row
    do_stats();

    __syncthreads();

    // ---- row-seam fixup: first row x block-circular previous strip's last row
    if (act) {
        const int ps = (strip + 3) & 3;
        float2 pv  = lastrow2[ps][lane];
        float2 lft = lastrow2[ps][lane == 0 ? 47 : lane - 1];
        float2 rgt = lastrow2[ps][lane == 47 ? 0 : lane + 1];
        upd2(2, firstN.x * pv.x,  firstN.y * pv.y);
        upd2(3, firstN.x * lft.y, firstN.y * pv.x);
        upd2(4, firstN.x * pv.y,  firstN.y * rgt.x);
    }

    // ---- reduce: 15 floats via shuffles; counts are wave-uniform scalars ----
    #pragma unroll
    for (int off = 32; off >= 1; off >>= 1)
        #pragma unroll
        for (int s = 0; s < 5; ++s) {
            acc[s][0] += __shfl_down(acc[s][0], off);
            acc[s][1] += __shfl_down(acc[s][1], off);
            acc[s][2] += __shfl_down(acc[s][2], off);
        }
    const int wv = strip;
    if (lane == 0) {
        #pragma unroll
        for (int s = 0; s < 5; ++s) {
            redf[wv][s*3+0] = acc[s][0];
            redf[wv][s*3+1] = acc[s][1];
            redf[wv][s*3+2] = acc[s][2];
            redc[wv][s*2+0] = (float)cl[s];
            redc[wv][s*2+1] = (float)cr[s];
        }
    }
    __syncthreads();
    if (tid < 15) {
        stats[((size_t)b * NBLK + bIdx) * 25 + tid] =
            redf[0][tid] + redf[1][tid] + redf[2][tid] + redf[3][tid];
    } else if (tid < 25) {
        int t = tid - 15;
        stats[((size_t)b * NBLK + bIdx) * 25 + tid] =
            redc[0][t] + redc[1][t] + redc[2][t] + redc[3][t];
    }
}

// ================= scale-2: scalar fused MSCN + stats (round-6, K=48) =========
template <int K, bool WDS>
__global__ __launch_bounds__(256) void fused_mscn_stats(
        const float* __restrict__ img, float* __restrict__ dsout,
        const float* __restrict__ w1d, float* __restrict__ stats) {
    constexpr int NSLAB = K / 48;
    constexpr int NSTRIP = 4 / NSLAB;
    constexpr int SROWS = K / NSTRIP;
    constexpr int W = K * NB;
    constexpr int H = W;

    __shared__ float lastrow[NSTRIP][K];
    __shared__ float redf[4][15];
    __shared__ float redc[4][10];

    const int tid = threadIdx.x;
    const int lane = tid & 63;
    const int wv = tid >> 6;
    const int slab = wv % NSLAB;
    const int strip = wv / NSLAB;
    const int bIdx = blockIdx.x;
    const int b = blockIdx.y;
    const int bh = bIdx / NB, bw = bIdx % NB;
    const int x0 = bw * K + slab * 48;
    const int gx = x0 - 3 + lane;
    const int gxc = min(max(gx, 0), W - 1);
    const int r0 = bh * K + strip * SROWS;
    const int basem3 = (lane - 3) << 2;
    const bool act = (lane >= 3) && (lane <= 50);
    int am1 = ((lane == 3) ? 50 : (lane - 1)) << 2;
    int ap1 = ((lane == 50) ? 3 : (lane + 1)) << 2;

    const float* im = img + (size_t)b * H * W + gxc;
    const float w0=w1d[0], w1=w1d[1], w2=w1d[2], w3=w1d[3], w4=w1d[4], w5=w1d[5], w6=w1d[6];

    auto ld = [&](int r) -> float {
        int rc = min(max(r, 0), H - 1);
        return im[(size_t)rc * W];
    };

    float pa0, pa1, pa2, pa4, pa5, pa6, vHp;
    auto issue_raw = [&](float v) {
        pa0 = bperm(basem3,      v);
        pa1 = bperm(basem3 + 4,  v);
        pa2 = bperm(basem3 + 8,  v);
        pa4 = bperm(basem3 + 16, v);
        pa5 = bperm(basem3 + 20, v);
        pa6 = bperm(basem3 + 24, v);
        vHp = v;
    };
    auto combine_raw = [&](float& om, float& oq) {
        om = ((w0*pa0 + w1*pa1) + (w2*pa2 + w3*vHp)) + ((w4*pa4 + w5*pa5) + w6*pa6);
        oq = ((w0*pa0*pa0 + w1*pa1*pa1) + (w2*pa2*pa2 + w3*vHp*vHp))
           + ((w4*pa4*pa4 + w5*pa5*pa5) + w6*pa6*pa6);
    };

    float acc[5][3];
    #pragma unroll
    for (int s = 0; s < 5; ++s) { acc[s][0] = acc[s][1] = acc[s][2] = 0.f; }
    int cl[5] = {0,0,0,0,0}, cr[5] = {0,0,0,0,0};

    auto upd = [&](int s, float v) {
        float vp = fmaxf(v, 0.f);
        acc[s][0] = fmaf(vp, vp, acc[s][0]);
        acc[s][1] = fmaf(v, v, acc[s][1]);
        acc[s][2] += fabsf(v);
        cl[s] += __popcll(__ballot(v < 0.f));
        cr[s] += __popcll(__ballot(v > 0.f));
    };

    float mr0,mr1,mr2,mr3,mr4,mr5,mr6, qr0,qr1,qr2,qr3,qr4,qr5,qr6;
    float rA, rB, rC, rD;
    float vN = ld(r0 - 3);
    { float v=vN; vN=ld(r0-2); issue_raw(v); combine_raw(mr0,qr0); }
    { float v=vN; vN=ld(r0-1); issue_raw(v); combine_raw(mr1,qr1); }
    { float v=vN; vN=ld(r0+0); issue_raw(v); combine_raw(mr2,qr2); }
    { float v=vN; vN=ld(r0+1); issue_raw(v); combine_raw(mr3,qr3); rA=v; }
    { float v=vN; vN=ld(r0+2); issue_raw(v); combine_raw(mr4,qr4); rB=v; }
    { float v=vN; vN=ld(r0+3); issue_raw(v); combine_raw(mr5,qr5); rC=v; }
    { float v=vN; vN=ld(r0+4); issue_raw(v); combine_raw(mr6,qr6); rD=v; }
    { float v=vN; vN=ld(r0+5); issue_raw(v); }

    float normP = 0.f, normP2 = 0.f;
    float pendSL = 0.f, pendPL = 0.f, pendPR = 0.f;
    float firstN = 0.f;

    #pragma unroll 4
    for (int yy = 0; yy < SROWS; ++yy) {
        const int y = r0 + yy;
        if (yy > 0) {
            upd(0, normP);
            upd(1, normP * pendSL);
            upd(2, normP * normP2);
            upd(3, normP * pendPL);
            upd(4, normP * pendPR);
        }
        float mu = ((w0*mr0 + w1*mr1) + (w2*mr2 + w3*mr3)) + ((w4*mr4 + w5*mr5) + w6*mr6);
        float s2 = ((w0*qr0 + w1*qr1) + (w2*qr2 + w3*qr3)) + ((w4*qr4 + w5*qr5) + w6*qr6);
        float sig = __builtin_amdgcn_sqrtf(fabsf(s2 - mu * mu));
        float nrm = (rA - mu) * __builtin_amdgcn_rcpf(sig + 1.0f);
        float cur = act ? nrm : 0.f;

        if (yy == 0) firstN = cur;
        if (yy == SROWS - 1 && act) lastrow[strip][slab * 48 + lane - 3] = cur;

        pendSL = bperm(am1, cur);
        pendPL = bperm(am1, normP);
        pendPR = bperm(ap1, normP);
        normP2 = normP; normP = cur;

        float mh, qh; combine_raw(mh, qh);
        mr0=mr1; mr1=mr2; mr2=mr3; mr3=mr4; mr4=mr5; mr5=mr6; mr6=mh;
        qr0=qr1; qr1=qr2; qr2=qr3; qr3=qr4; qr4=qr5; qr5=qr6; qr6=qh;

        rA=rB; rB=rC; rC=rD; rD=vHp;
        float vv = vN; vN = ld(y + 6);
        issue_raw(vv);
    }
    upd(0, normP);
    upd(1, normP * pendSL);
    upd(2, normP * normP2);
    upd(3, normP * pendPL);
    upd(4, normP * pendPR);

    __syncthreads();

    {
        const int ps = (strip + NSTRIP - 1) % NSTRIP;
        int j  = slab * 48 + (lane - 3);
        int js = act ? j : 0;
        int jm1 = (js + K - 1) % K;
        int jp1 = (js + 1) % K;
        float pv  = act ? lastrow[ps][js]  : 0.f;
        float pvL = act ? lastrow[ps][jm1] : 0.f;
        float pvR = act ? lastrow[ps][jp1] : 0.f;
        upd(2, firstN * pv);
        upd(3, firstN * pvL);
        upd(4, firstN * pvR);
    }

    #pragma unroll
    for (int off = 32; off >= 1; off >>= 1)
        #pragma unroll
        for (int s = 0; s < 5; ++s) {
            acc[s][0] += __shfl_down(acc[s][0], off);
            acc[s][1] += __shfl_down(acc[s][1], off);
            acc[s][2] += __shfl_down(acc[s][2], off);
        }
    if (lane == 0) {
        #pragma unroll
        for (int s = 0; s < 5; ++s) {
            redf[wv][s*3+0] = acc[s][0];
            redf[wv][s*3+1] = acc[s][1];
            redf[wv][s*3+2] = acc[s][2];
            redc[wv][s*2+0] = (float)cl[s];
            redc[wv][s*2+1] = (float)cr[s];
        }
    }
    __syncthreads();
    if (tid < 15) {
        stats[((size_t)b * NBLK + bIdx) * 25 + tid] =
            redf[0][tid] + redf[1][tid] + redf[2][tid] + redf[3][tid];
    } else if (tid < 25) {
        int t = tid - 15;
        stats[((size_t)b * NBLK + bIdx) * 25 + tid] =
            redc[0][t] + redc[1][t] + redc[2][t] + redc[3][t];
    }
}

// ---------------- AGGD closed-form + binary-search argmin ----------------
__global__ __launch_bounds__(256) void aggd_kernel(
        const float* __restrict__ stats1, const float* __restrict__ stats2,
        const float* __restrict__ rgam, const float* __restrict__ convt,
        const float* __restrict__ meanf, float* __restrict__ feats) {
    __shared__ float rg[NGRID];
    for (int i = threadIdx.x; i < NGRID; i += 256) rg[i] = rgam[i];
    __syncthreads();

    int gid = blockIdx.x * 256 + threadIdx.x;
    if (gid >= 2 * BATCH * NBLK * 5) return;
    int s = gid % 5; int t = gid / 5;
    int blk = t % NBLK; t /= NBLK;
    int b = t % BATCH; int scale = t / BATCH;

    const float* st = (scale ? stats2 : stats1) + ((size_t)b * NBLK + blk) * 25;
    float sr2 = st[s*3+0], ssq = st[s*3+1], sab = st[s*3+2];
    float cl = st[15 + 2*s], cr = st[15 + 2*s + 1];
    float sl2 = fmaxf(ssq - sr2, 0.f);
    float n = scale ? (48.f * 48.f) : (96.f * 96.f);

    float lstd = sqrtf(sl2 / (cl + 1e-8f));
    float rstd = sqrtf(sr2 / (cr + 1e-8f));
    float gh = lstd / rstd;
    float mab = sab / n;
    float msq = ssq / n;
    float rhat = mab * mab / msq;
    float g2 = gh * gh;
    float x = rhat * (gh * g2 + 1.f) * (gh + 1.f) / ((g2 + 1.f) * (g2 + 1.f));

    int lo = 0, hi = NGRID;
    while (lo < hi) {
        int mid = (lo + hi) >> 1;
        if (rg[mid] < x) lo = mid + 1; else hi = mid;
    }
    int gi;
    if (lo <= 0) gi = 0;
    else if (lo >= NGRID) gi = NGRID - 1;
    else {
        float dlo = x - rg[lo - 1];
        float dhi = rg[lo] - x;
        gi = (dlo <= dhi) ? lo - 1 : lo;
    }

    float alpha = (float)(0.2 + 0.001 * (double)gi);
    float cv = convt[gi];
    float lb = lstd * cv, rb = rstd * cv;
    float* fo = feats + ((size_t)b * NBLK + blk) * NFEAT + (scale ? 18 : 0);
    if (s == 0) {
        fo[0] = alpha;
        fo[1] = 0.5f * (lb + rb);
    } else {
        int o = 2 + (s - 1) * 4;
        fo[o]     = alpha;
        fo[o + 1] = (rb - lb) * meanf[gi];
        fo[o + 2] = lb;
        fo[o + 3] = rb;
    }
}

// ---------------- per-batch covariance + solve + score ----------------
__global__ __launch_bounds__(256) void score_kernel(
        const float* __restrict__ feats, const float* __restrict__ mu_pris,
        const float* __restrict__ cov_pris, float* __restrict__ out) {
    __shared__ float F[NBLK][NFEAT];
    __shared__ double mu[NFEAT];
    __shared__ double A[NFEAT][NFEAT + 1];
    __shared__ double dff[NFEAT];
    __shared__ double xs[NFEAT];
    int b = blockIdx.x, tid = threadIdx.x;
    const float* fp = feats + (size_t)b * NBLK * NFEAT;
    for (int i = tid; i < NBLK * NFEAT; i += 256) F[i / NFEAT][i % NFEAT] = fp[i];
    __syncthreads();
    if (tid < NFEAT) {
        double s = 0.0;
        for (int n = 0; n < NBLK; ++n) s += (double)F[n][tid];
        mu[tid] = s / (double)NBLK;
        dff[tid] = (double)mu_pris[tid] - mu[tid];
    }
    __syncthreads();
    for (int e = tid; e < NFEAT * NFEAT; e += 256) {
        int f = e / NFEAT, g = e % NFEAT;
        double mf = mu[f], mg = mu[g];
        double s = 0.0;
        for (int n = 0; n < NBLK; ++n) s += ((double)F[n][f] - mf) * ((double)F[n][g] - mg);
        A[f][g] = (s / (double)(NBLK - 1) + (double)cov_pris[f * NFEAT + g]) * 0.5;
    }
    if (tid < NFEAT) A[tid][NFEAT] = dff[tid];
    for (int k = 0; k < NFEAT - 1; ++k) {
        __syncthreads();
        double rk = 1.0 / A[k][k];
        for (int e = tid; e < NFEAT * (NFEAT + 1); e += 256) {
            int r = e / (NFEAT + 1), c = e % (NFEAT + 1);
            if (r > k && c > k) A[r][c] -= (A[r][k] * rk) * A[k][c];
        }
    }
    __syncthreads();
    for (int i = NFEAT - 1; i >= 0; --i) {
        if (tid == i) xs[i] = A[i][NFEAT] / A[i][i];
        __syncthreads();
        if (tid < i) A[tid][NFEAT] -= A[tid][i] * xs[i];
    }
    __syncthreads();
    if (tid == 0) {
        double quad = 0.0;
        for (int i = 0; i < NFEAT; ++i) quad += dff[i] * xs[i];
        out[b] = (float)sqrt(fmax(quad, 0.0));
    }
}

// ---------------- launch ----------------
extern "C" void kernel_launch(void* const* d_in, const int* in_sizes, int n_in,
                              void* d_out, int out_size, void* d_ws, size_t ws_size,
                              hipStream_t stream) {
    const float* img      = (const float*)d_in[0];
    const float* mu_pris  = (const float*)d_in[1];
    const float* cov_pris = (const float*)d_in[2];
    float* out = (float*)d_out;
    float* ws = (float*)d_ws;

    float* rgam  = ws;                 // 9801 (pad to 9856)
    float* convt = rgam + 9856;
    float* meanf = convt + 9856;
    float* w1d   = meanf + 9856;       // 8
    float* stats1 = w1d + 8;                           // 16*121*25
    float* stats2 = stats1 + BATCH * NBLK * 25;
    float* feats  = stats2 + BATCH * NBLK * 25;        // 16*121*36
    float* dsimg  = feats + BATCH * NBLK * NFEAT;      // 16*528*528

    init_tables<<<(NGRID + 255) / 256, 256, 0, stream>>>(rgam, convt, meanf, w1d);

    fused96<<<dim3(NBLK, BATCH), 256, 0, stream>>>(img, dsimg, w1d, stats1);
    fused_mscn_stats<48, false><<<dim3(NBLK, BATCH), 256, 0, stream>>>(
        dsimg, nullptr, w1d, stats2);

    aggd_kernel<<<(2 * BATCH * NBLK * 5 + 255) / 256, 256, 0, stream>>>(
        stats1, stats2, rgam, convt, meanf, feats);

    score_kernel<<<BATCH, 256, 0, stream>>>(feats, mu_pris, cov_pris, out);
}